// Round 9
// baseline (159.488 us; speedup 1.0000x reference)
//
#include <hip/hip_runtime.h>
#include <stdint.h>
#include <math.h>

static constexpr int NIMG  = 16;
static constexpr int HH    = 512;
static constexpr int WW    = 512;
static constexpr int TOTAL = NIMG * HH * WW;   // 4,194,304
static constexpr int WPR   = WW / 64;          // 8 qwords per row
static constexpr int QPI   = HH * WPR;         // 4096 qwords per image
static constexpr int NQ    = TOTAL / 64;       // 65,536
static constexpr int MAXIT = 128;
static constexpr int PR    = 11;               // padded LDS row stride in qwords (88B; 22g mod 32 distinct)
static constexpr int PROWS = HH + 2;           // 514 rows (zero margins top/bottom)
static constexpr int LQ    = PROWS * PR;       // 5654 qwords per buffer

// workspace layout (bytes)
static constexpr size_t OFF_PACK = 0;                      // u64[NQ] packed bitmap
static constexpr size_t OFF_TICK = (size_t)NQ * 8;         // int ticket (+pad to 8)
static constexpr size_t OFF_PART = OFF_TICK + 8;           // double[NIMG*2]

#define LD_RLX(p)   __hip_atomic_load((p), __ATOMIC_RELAXED, __HIP_MEMORY_SCOPE_AGENT)

// gaussian taps exactly like numpy (f64 exp, sequential /sum, cast f32) — bit-compatible (r5-r8: absmax 0)
__device__ __forceinline__ void make_gk(float* gks) {
    if (threadIdx.x < 9) {
        double ssum = 0.0;
        for (int i = 0; i < 9; ++i) { double x = (double)(i - 4); ssum += exp(-0.5 * x * x); }
        double x = (double)((int)threadIdx.x - 4);
        gks[threadIdx.x] = (float)(exp(-0.5 * x * x) / ssum);
    }
}

// --- fused separable blur + threshold + bit-pack. 64x64 output tile per block. (unchanged since r5)
__global__ void __launch_bounds__(256) fused_blur(const float* __restrict__ gt,
                                                  uint64_t* __restrict__ packed,
                                                  int* __restrict__ tick) {
    __shared__ float tin[72 * 72];
    __shared__ float tv[64 * 72];
    __shared__ float gks[9];
    const int tid = threadIdx.x;
    if (blockIdx.x == 0 && tid == 0) *tick = 0;      // ws is re-poisoned before every timed call
    make_gk(gks);
    const int img  = blockIdx.x >> 6;
    const int tile = blockIdx.x & 63;
    const int oy = (tile >> 3) << 6, ox = (tile & 7) << 6;
    const float* G = gt + (size_t)img * (HH * WW);
    for (int i = tid; i < 72 * 72; i += 256) {
        int r = i / 72, c = i - r * 72;
        int gy = oy - 4 + r, gx = ox - 4 + c;
        gy = gy < 0 ? -gy - 1 : (gy >= HH ? 2 * HH - 1 - gy : gy);   // symmetric pad
        gx = gx < 0 ? -gx - 1 : (gx >= WW ? 2 * WW - 1 - gx : gx);
        tin[i] = G[gy * WW + gx];
    }
    __syncthreads();
    for (int i = tid; i < 64 * 72; i += 256) {       // vertical pass first (axis=1, like ref)
        int r = i / 72, c = i - r * 72;
        float s = 0.f;
#pragma unroll
        for (int t = 0; t < 9; ++t) s += gks[t] * tin[(r + t) * 72 + c];
        tv[i] = s;
    }
    __syncthreads();
    const int lane = tid & 63, w = tid >> 6;
    for (int j = 0; j < 16; ++j) {                   // horizontal pass + threshold + pack
        int yr = w * 16 + j;
        float s = 0.f;
#pragma unroll
        for (int t = 0; t < 9; ++t) s += gks[t] * tv[yr * 72 + lane + t];
        uint64_t m = __ballot(s > 0.1f);
        if (lane == 0) packed[(size_t)img * QPI + (oy + yr) * WPR + (ox >> 6)] = m;
    }
}

// full adder on 64 bit-lanes
__device__ __forceinline__ void fa(uint64_t a, uint64_t b, uint64_t c, uint64_t& s, uint64_t& cy) {
    uint64_t axb = a ^ b;
    s  = axb ^ c;
    cy = (a & b) | (c & axb);
}

// bit-sliced Zhang-Suen delete mask (verified exact, rounds 2-8)
__device__ __forceinline__ uint64_t zs_del(uint64_t cc, uint64_t nc, uint64_t sc, uint64_t cw, uint64_t ce,
                                           uint64_t nw, uint64_t ne, uint64_t sw, uint64_t se, int step) {
    uint64_t p2 = nc;
    uint64_t p3 = (nc >> 1) | (ne << 63);
    uint64_t p4 = (cc >> 1) | (ce << 63);
    uint64_t p5 = (sc >> 1) | (se << 63);
    uint64_t p6 = sc;
    uint64_t p7 = (sc << 1) | (sw >> 63);
    uint64_t p8 = (cc << 1) | (cw >> 63);
    uint64_t p9 = (nc << 1) | (nw >> 63);

    uint64_t s1, k1, s2, k2;
    fa(p2, p3, p4, s1, k1);
    fa(p5, p6, p7, s2, k2);
    uint64_t s3 = p8 ^ p9, k3 = p8 & p9;
    uint64_t b0, k4;
    fa(s1, s2, s3, b0, k4);
    uint64_t t1, t2;
    fa(k1, k2, k3, t1, t2);
    uint64_t b1 = t1 ^ k4;
    uint64_t k5 = t1 & k4;
    uint64_t b2 = t2 ^ k5;
    uint64_t b3 = t2 & k5;
    uint64_t condB = (b1 | b2 | b3) & ~(b3 | (b0 & b1 & b2));

    uint64_t q0 = ~p2 & p3, q1 = ~p3 & p4, q2 = ~p4 & p5, q3 = ~p5 & p6;
    uint64_t q4 = ~p6 & p7, q5 = ~p7 & p8, q6 = ~p8 & p9, q7 = ~p9 & p2;
    uint64_t u1, v1, u2, v2;
    fa(q0, q1, q2, u1, v1);
    fa(q3, q4, q5, u2, v2);
    uint64_t u3 = q6 ^ q7, v3 = q6 & q7;
    uint64_t a0, v4;
    fa(u1, u2, u3, a0, v4);
    uint64_t w1, w2;
    fa(v1, v2, v3, w1, w2);
    uint64_t a1 = w1 ^ v4;
    uint64_t ka = w1 & v4;
    uint64_t a2 = w2 ^ ka;
    uint64_t a3 = w2 & ka;
    uint64_t condA = a0 & ~a1 & ~a2 & ~a3;

    uint64_t nc1, nc2;
    if (step == 0) { nc1 = ~(p2 & p4 & p6); nc2 = ~(p4 & p6 & p8); }
    else           { nc1 = ~(p2 & p4 & p8); nc2 = ~(p2 & p6 & p8); }

    return cc & condB & condA & nc1 & nc2;
}

// one sub-step: thread walks a 4-row column, rotating row registers; zero margins -> no bounds checks
__device__ __forceinline__ int zs_sub(const uint64_t* __restrict__ cur, uint64_t* __restrict__ nxt,
                                      int step, int b0) {
    int ch = 0;
    int b = b0;
    uint64_t nwr = cur[b - PR - 1], ncr = cur[b - PR], ner = cur[b - PR + 1];
    uint64_t cwr = cur[b - 1],      ccr = cur[b],      cer = cur[b + 1];
#pragma unroll
    for (int r = 0; r < 4; ++r) {
        uint64_t swr = cur[b + PR - 1], scr = cur[b + PR], ser = cur[b + PR + 1];
        uint64_t out = ccr;
        if (ccr) {
            uint64_t del = zs_del(ccr, ncr, scr, cwr, cer, nwr, ner, swr, ser, step);
            out = ccr & ~del;
            ch |= (del != 0ull);
        }
        nxt[b] = out;
        nwr = cwr; ncr = ccr; ner = cer;
        cwr = swr; ccr = scr; cer = ser;
        b += PR;
    }
    return ch;
}

// --- mega kernel: one block per image. Thin in LDS to convergence, then reduce own image's loss
// against the LDS mask; 16-way ticket, last block sums 32 doubles and writes the scalar loss.
__global__ void __launch_bounds__(1024) mega_kernel(const uint64_t* __restrict__ packed,
                                                    const float4* __restrict__ pred4,
                                                    const float4* __restrict__ gt4,
                                                    double* __restrict__ part,
                                                    int* __restrict__ tick,
                                                    float* __restrict__ out) {
    __shared__ uint64_t SA[LQ];        // 45,232 B (padded: rows 0/513 and cols 0/9/10 stay zero)
    __shared__ uint64_t SB[LQ];
    __shared__ double sh0[1024];
    __shared__ double sh1[1024];
    __shared__ int f2[2];
    __shared__ int lastf;
    const int tid = threadIdx.x;
    const int img = blockIdx.x;
    const uint64_t* gimg = packed + (size_t)img * QPI;

    // zero both buffers (margins must be 0 forever), then load image into interior
    for (int i = tid; i < LQ; i += 1024) { SA[i] = 0; SB[i] = 0; }
    __syncthreads();
    for (int i = tid; i < QPI; i += 1024)
        SA[((i >> 3) + 1) * PR + (i & 7) + 1] = gimg[i];
    if (tid == 0) { f2[0] = 0; f2[1] = 0; }
    __syncthreads();

    const int b0 = ((tid >> 3) * 4 + 1) * PR + (tid & 7) + 1;

    for (int it = 0; it < MAXIT; ++it) {
        const int p = it & 1;
        int ch = zs_sub(SA, SB, 0, b0);
        __syncthreads();                         // SB complete; f2[p^1] reset visible
        ch |= zs_sub(SB, SA, 1, b0);
        if (__any(ch) && (tid & 63) == 0) atomicOr(&f2[p], 1);
        __syncthreads();                         // SA complete; all atomicOrs into f2[p] done
        int stop = (f2[p] == 0);                 // uniform read
        if (tid == 0) f2[p ^ 1] = 0;             // reset other parity; ordered by next iter's barriers
        if (stop) break;
    }
    // SA holds the converged mask (always lands in SA after a full iteration)

    // --- fused loss reduction for this image (mask straight from LDS)
    double a0 = 0.0, a1 = 0.0;
    const int N4I = HH * WW / 4;                 // 65,536 float4 per image
    const float4* P = pred4 + (size_t)img * N4I;
    const float4* G = gt4   + (size_t)img * N4I;
    for (int i = tid; i < N4I; i += 1024) {
        float4 pv = P[i];
        float4 gv = G[i];
        int row = i >> 7, c4 = i & 127;          // 128 float4 per row
        uint64_t mq = SA[(row + 1) * PR + (c4 >> 4) + 1];
        int shb = (c4 & 15) << 2;
        double d, d2;
        d = (double)(pv.x - gv.x); d2 = d * d; a0 += d2; if ((mq >> (shb    )) & 1) a1 += d2;
        d = (double)(pv.y - gv.y); d2 = d * d; a0 += d2; if ((mq >> (shb + 1)) & 1) a1 += d2;
        d = (double)(pv.z - gv.z); d2 = d * d; a0 += d2; if ((mq >> (shb + 2)) & 1) a1 += d2;
        d = (double)(pv.w - gv.w); d2 = d * d; a0 += d2; if ((mq >> (shb + 3)) & 1) a1 += d2;
    }
    sh0[tid] = a0;
    sh1[tid] = a1;
    __syncthreads();
    for (int off = 512; off > 0; off >>= 1) {
        if (tid < off) { sh0[tid] += sh0[tid + off]; sh1[tid] += sh1[tid + off]; }
        __syncthreads();
    }
    if (tid == 0) {
        part[2 * img]     = sh0[0];
        part[2 * img + 1] = sh1[0];
        int pos = __hip_atomic_fetch_add(tick, 1, __ATOMIC_ACQ_REL, __HIP_MEMORY_SCOPE_AGENT);
        lastf = (pos == NIMG - 1);               // release orders part stores; acquire sees others'
    }
    __syncthreads();
    if (lastf) {
        if (tid < 2 * NIMG) sh0[tid] = LD_RLX(&part[tid]);
        __syncthreads();
        if (tid == 0) {
            double a = 0.0;
            for (int i = 0; i < 2 * NIMG; ++i) a += sh0[i];
            out[0] = (float)(0.5 * a / (double)TOTAL);
        }
    }
}

extern "C" void kernel_launch(void* const* d_in, const int* in_sizes, int n_in,
                              void* d_out, int out_size, void* d_ws, size_t ws_size,
                              hipStream_t stream) {
    const float* pred = (const float*)d_in[0];
    const float* gt   = (const float*)d_in[1];
    char* ws = (char*)d_ws;
    uint64_t* packed = (uint64_t*)(ws + OFF_PACK);
    int*      tick   = (int*)(ws + OFF_TICK);
    double*   part   = (double*)(ws + OFF_PART);

    fused_blur<<<NIMG * 64, 256, 0, stream>>>(gt, packed, tick);
    mega_kernel<<<NIMG, 1024, 0, stream>>>(packed, (const float4*)pred, (const float4*)gt,
                                           part, tick, (float*)d_out);
}